// Round 1
// baseline (3597.791 us; speedup 1.0000x reference)
//
#include <hip/hip_runtime.h>
#include <hip/hip_bf16.h>

// Problem constants: B=256, I=512, R=1024, L=2, U=11 (only 10 steps matter).
#define B_N 256
#define R_N 1024
#define U_N 11

typedef __attribute__((ext_vector_type(8))) short bf16x8;
typedef __attribute__((ext_vector_type(4))) float f32x4;

__device__ __forceinline__ float sigmoid_f(float x) {
    return 1.0f / (1.0f + __expf(-x));
}

__device__ __forceinline__ float tanh_f(float x) {
    x = fminf(15.0f, fmaxf(-15.0f, x));
    const float e = __expf(2.0f * x);
    return (e - 1.0f) / (e + 1.0f);
}

__device__ __forceinline__ short bf16_of(float x) {
    union { __hip_bfloat16 h; short s; } u;
    u.h = __float2bfloat16(x);
    return u.s;
}

__device__ __forceinline__ bf16x8 pack8(const float* __restrict__ p) {
    const float4 v0 = *reinterpret_cast<const float4*>(p);
    const float4 v1 = *reinterpret_cast<const float4*>(p + 4);
    bf16x8 r;
    r[0] = bf16_of(v0.x); r[1] = bf16_of(v0.y);
    r[2] = bf16_of(v0.z); r[3] = bf16_of(v0.w);
    r[4] = bf16_of(v1.x); r[5] = bf16_of(v1.y);
    r[6] = bf16_of(v1.z); r[7] = bf16_of(v1.w);
    return r;
}

// One LSTM layer at one step:  pre = A1 @ W1^T + A2 @ W2^T + bi + bh, then cell.
// W1: (4R, K1) row-major, W2: (4R, K2) row-major.
// Each wave: M=32 (2 m-frags), 16 r-columns, 4 gates -> 8 MFMAs per K-chunk.
// Block = 2 waves (r-width 32). Grid = (R/32=32, B/32=8) = 256 blocks.
__global__ __launch_bounds__(128) void lstm_layer(
    const float* __restrict__ A1, int lda1, int K1, const float* __restrict__ W1,
    const float* __restrict__ A2, int lda2, int K2, const float* __restrict__ W2,
    const float* __restrict__ bi, const float* __restrict__ bh,
    float* __restrict__ c_state,
    float* __restrict__ h_out, int ldh)
{
    const int lane = threadIdx.x & 63;
    const int wave = threadIdx.x >> 6;
    const int ln = lane & 15;         // row-within-fragment (m or n)
    const int lk = (lane >> 4) * 8;   // k-offset within 32-chunk
    const int m_base = blockIdx.y * 32;
    const int rb = blockIdx.x * 32 + wave * 16;

    f32x4 acc[2][4];
#pragma unroll
    for (int mf = 0; mf < 2; ++mf)
#pragma unroll
        for (int g = 0; g < 4; ++g) {
            f32x4 z = {0.0f, 0.0f, 0.0f, 0.0f};
            acc[mf][g] = z;
        }

#pragma unroll 1
    for (int part = 0; part < 2; ++part) {
        const float* A  = part ? A2 : A1;
        const int   lda = part ? lda2 : lda1;
        const int   K   = part ? K2 : K1;
        const float* W  = part ? W2 : W1;

        const float* ap0 = A + (size_t)(m_base + ln) * lda + lk;
        const float* ap1 = A + (size_t)(m_base + 16 + ln) * lda + lk;
        const float* wp0 = W + (size_t)(0 * R_N + rb + ln) * K + lk;
        const float* wp1 = W + (size_t)(1 * R_N + rb + ln) * K + lk;
        const float* wp2 = W + (size_t)(2 * R_N + rb + ln) * K + lk;
        const float* wp3 = W + (size_t)(3 * R_N + rb + ln) * K + lk;

#pragma unroll 2
        for (int k = 0; k < K; k += 32) {
            const bf16x8 a0 = pack8(ap0 + k);
            const bf16x8 a1 = pack8(ap1 + k);
            const bf16x8 b0 = pack8(wp0 + k);
            const bf16x8 b1 = pack8(wp1 + k);
            const bf16x8 b2 = pack8(wp2 + k);
            const bf16x8 b3 = pack8(wp3 + k);
            acc[0][0] = __builtin_amdgcn_mfma_f32_16x16x32_bf16(a0, b0, acc[0][0], 0, 0, 0);
            acc[1][0] = __builtin_amdgcn_mfma_f32_16x16x32_bf16(a1, b0, acc[1][0], 0, 0, 0);
            acc[0][1] = __builtin_amdgcn_mfma_f32_16x16x32_bf16(a0, b1, acc[0][1], 0, 0, 0);
            acc[1][1] = __builtin_amdgcn_mfma_f32_16x16x32_bf16(a1, b1, acc[1][1], 0, 0, 0);
            acc[0][2] = __builtin_amdgcn_mfma_f32_16x16x32_bf16(a0, b2, acc[0][2], 0, 0, 0);
            acc[1][2] = __builtin_amdgcn_mfma_f32_16x16x32_bf16(a1, b2, acc[1][2], 0, 0, 0);
            acc[0][3] = __builtin_amdgcn_mfma_f32_16x16x32_bf16(a0, b3, acc[0][3], 0, 0, 0);
            acc[1][3] = __builtin_amdgcn_mfma_f32_16x16x32_bf16(a1, b3, acc[1][3], 0, 0, 0);
        }
    }

    // Epilogue: C/D layout col = lane&15, row = (lane>>4)*4 + t.
    const int r = rb + ln;
    const float bI = bi[0 * R_N + r] + bh[0 * R_N + r];
    const float bF = bi[1 * R_N + r] + bh[1 * R_N + r];
    const float bO = bi[2 * R_N + r] + bh[2 * R_N + r];
    const float bG = bi[3 * R_N + r] + bh[3 * R_N + r];
    const int mrow = (lane >> 4) * 4;

#pragma unroll
    for (int mf = 0; mf < 2; ++mf) {
#pragma unroll
        for (int t = 0; t < 4; ++t) {
            const int m = m_base + mf * 16 + mrow + t;
            const float iv = sigmoid_f(acc[mf][0][t] + bI);
            const float fv = sigmoid_f(acc[mf][1][t] + bF);
            const float ov = sigmoid_f(acc[mf][2][t] + bO);
            const float gv = tanh_f(acc[mf][3][t] + bG);
            const size_t ci = (size_t)m * R_N + r;
            const float c = fv * c_state[ci] + iv * gv;
            c_state[ci] = c;
            h_out[(size_t)m * ldh + r] = ov * tanh_f(c);
        }
    }
}

// Unpack init_states_input (B, 4, R) -> h0 ws, c0 ws, out slot 0 (h1), c1 ws.
__global__ __launch_bounds__(256) void init_states(
    const float* __restrict__ st, float* __restrict__ h0,
    float* __restrict__ c0, float* __restrict__ c1, float* __restrict__ out)
{
    const int idx = blockIdx.x * 256 + threadIdx.x;  // 0 .. 256*1024-1
    const int b = idx >> 10;
    const int r = idx & 1023;
    const float* s = st + (size_t)b * 4096;
    h0[idx] = s[r];
    c0[idx] = s[1024 + r];
    out[(size_t)b * (U_N * R_N) + r] = s[2048 + r];
    c1[idx] = s[3072 + r];
}

extern "C" void kernel_launch(void* const* d_in, const int* in_sizes, int n_in,
                              void* d_out, int out_size, void* d_ws, size_t ws_size,
                              hipStream_t stream)
{
    const float* x   = (const float*)d_in[0];
    const float* st  = (const float*)d_in[1];
    const float* Wi0 = (const float*)d_in[2];
    const float* bi0 = (const float*)d_in[3];
    const float* Wh0 = (const float*)d_in[4];
    const float* bh0 = (const float*)d_in[5];
    const float* Wi1 = (const float*)d_in[6];
    const float* bi1 = (const float*)d_in[7];
    const float* Wh1 = (const float*)d_in[8];
    const float* bh1 = (const float*)d_in[9];
    float* out = (float*)d_out;

    float* h0a = (float*)d_ws;
    float* h0b = h0a + B_N * R_N;
    float* c0  = h0b + B_N * R_N;
    float* c1  = c0 + B_N * R_N;

    init_states<<<dim3((B_N * R_N) / 256), 256, 0, stream>>>(st, h0a, c0, c1, out);

    const dim3 grid(R_N / 32, B_N / 32);  // (32, 8) = 256 blocks
    for (int u = 0; u < 10; ++u) {
        const float* h0_in = (u & 1) ? h0b : h0a;
        float* h0_out      = (u & 1) ? h0a : h0b;
        // Layer 0: pre0 = x @ Wi0[u]^T + h0 @ Wh0[u]^T + bi0[u] + bh0[u]
        lstm_layer<<<grid, 128, 0, stream>>>(
            x, 512, 512, Wi0 + (size_t)u * 4096 * 512,
            h0_in, R_N, R_N, Wh0 + (size_t)u * 4096 * 1024,
            bi0 + (size_t)u * 4096, bh0 + (size_t)u * 4096,
            c0, h0_out, R_N);
        // Layer 1: pre1 = h0n @ Wi1[u]^T + h1 @ Wh1[u]^T + bi1[u] + bh1[u]
        //   h1 input lives in out slot u; h1 output goes to out slot u+1.
        lstm_layer<<<grid, 128, 0, stream>>>(
            h0_out, R_N, R_N, Wi1 + (size_t)u * 4096 * 1024,
            out + (size_t)u * R_N, U_N * R_N, R_N, Wh1 + (size_t)u * 4096 * 1024,
            bi1 + (size_t)u * 4096, bh1 + (size_t)u * 4096,
            c1, out + (size_t)(u + 1) * R_N, U_N * R_N);
    }
}

// Round 2
// 1227.799 us; speedup vs baseline: 2.9303x; 2.9303x over previous
//
#include <hip/hip_runtime.h>
#include <hip/hip_bf16.h>

// B=256, I=512, R=1024, L=2, U=11 (step 10's compute is dead; only 10 steps run).
#define B_N 256
#define R_N 1024
#define U_N 11
#define BK 32
#define SP 40   // LDS row stride in bf16 elems (BK+8): 80B rows, 16B-aligned frags

typedef __attribute__((ext_vector_type(8))) short bf16x8;
typedef __attribute__((ext_vector_type(4))) float f32x4;

__device__ __forceinline__ float sigmoid_f(float x) {
    return 1.0f / (1.0f + __expf(-x));
}

__device__ __forceinline__ float tanh_f(float x) {
    x = fminf(15.0f, fmaxf(-15.0f, x));
    const float e = __expf(2.0f * x);
    return (e - 1.0f) / (e + 1.0f);
}

__device__ __forceinline__ short bf16_of(float x) {
    union { __hip_bfloat16 h; short s; } u;
    u.h = __float2bfloat16(x);
    return u.s;
}

__device__ __forceinline__ short4 pack4(float4 v) {
    short4 r;
    r.x = bf16_of(v.x); r.y = bf16_of(v.y);
    r.z = bf16_of(v.z); r.w = bf16_of(v.w);
    return r;
}

// One LSTM layer: pre = A1 @ W1^T + A2 @ W2^T + bi + bh -> cell -> h_out, c_state.
// Block: 512 threads = 8 waves = (2 K-groups) x (4 gates).
// Block tile: M=32 rows x r=32 columns x 4 gates. Grid (R/32=32, B/32=8).
// Each wave: 2 m-frags x 2 r-frags for its gate, over its half of virtual K.
__global__ __launch_bounds__(512) void lstm_layer(
    const float* __restrict__ A1, int lda1, int K1, const float* __restrict__ W1,
    const float* __restrict__ A2, int lda2, int K2, const float* __restrict__ W2,
    const float* __restrict__ bi, const float* __restrict__ bh,
    float* __restrict__ c_state,
    float* __restrict__ h_out, int ldh)
{
    __shared__ __align__(16) short sA[2][32 * SP];    // [group][m*SP + k]
    __shared__ __align__(16) short sW[2][128 * SP];   // [group][(gate*32+rr)*SP + k]
    __shared__ float sPre[2][4 * 32 * 32];            // [group][(gate*32+m)*32 + r]

    const int tid  = threadIdx.x;
    const int lane = tid & 63;
    const int wave = tid >> 6;
    const int group = wave >> 2;      // K-half
    const int gate  = wave & 3;
    const int ln   = lane & 15;
    const int quad = lane >> 4;
    const int lk   = quad * 8;        // k offset within chunk (bf16 elems)
    const int tg   = tid & 255;       // thread index within its K-group

    const int m_base = blockIdx.y * 32;
    const int rb     = blockIdx.x * 32;

    const int Ktot  = K1 + K2;
    const int Khalf = Ktot >> 1;
    const int NC    = Khalf / BK;

    // Staging coords (per-thread, constant across chunks)
    const int arow = tg >> 3;          // 0..31
    const int acol = (tg & 7) * 4;     // 0,4,..,28

    f32x4 acc[2][2];
#pragma unroll
    for (int mf = 0; mf < 2; ++mf)
#pragma unroll
        for (int rf = 0; rf < 2; ++rf) {
            f32x4 z = {0.0f, 0.0f, 0.0f, 0.0f};
            acc[mf][rf] = z;
        }

    float4 pA;
    float4 pW[4];

    // ---- chunk loader: global -> registers (coalesced: 8 lanes cover one 128B row seg)
    auto load_chunk = [&](int c) {
        const int kv = group * Khalf + c * BK;
        const float* Ap; int lda; const float* Wp; int ldw; int kc;
        if (kv < K1) { Ap = A1; lda = lda1; Wp = W1; ldw = K1; kc = kv; }
        else         { Ap = A2; lda = lda2; Wp = W2; ldw = K2; kc = kv - K1; }
        pA = *reinterpret_cast<const float4*>(
            Ap + (size_t)(m_base + arow) * lda + kc + acol);
#pragma unroll
        for (int l = 0; l < 4; ++l) {
            const int wrow = l * 32 + (tg >> 3);   // 0..127 = gate*32 + rr
            const int g = wrow >> 5, rr = wrow & 31;
            pW[l] = *reinterpret_cast<const float4*>(
                Wp + (size_t)(g * R_N + rb + rr) * ldw + kc + acol);
        }
    };

    // ---- stager: registers -> LDS (fp32 -> bf16)
    auto store_chunk = [&]() {
        *reinterpret_cast<short4*>(&sA[group][arow * SP + acol]) = pack4(pA);
#pragma unroll
        for (int l = 0; l < 4; ++l) {
            const int wrow = l * 32 + (tg >> 3);
            *reinterpret_cast<short4*>(&sW[group][wrow * SP + acol]) = pack4(pW[l]);
        }
    };

    load_chunk(0);
#pragma unroll 1
    for (int c = 0; c < NC; ++c) {
        __syncthreads();                    // prior chunk's ds_reads done
        store_chunk();
        if (c + 1 < NC) load_chunk(c + 1);  // prefetch overlaps MFMA below
        __syncthreads();                    // staging visible

        bf16x8 af[2], wf[2];
#pragma unroll
        for (int mf = 0; mf < 2; ++mf)
            af[mf] = *reinterpret_cast<const bf16x8*>(
                &sA[group][(mf * 16 + ln) * SP + lk]);
#pragma unroll
        for (int rf = 0; rf < 2; ++rf)
            wf[rf] = *reinterpret_cast<const bf16x8*>(
                &sW[group][(gate * 32 + rf * 16 + ln) * SP + lk]);

        acc[0][0] = __builtin_amdgcn_mfma_f32_16x16x32_bf16(af[0], wf[0], acc[0][0], 0, 0, 0);
        acc[1][0] = __builtin_amdgcn_mfma_f32_16x16x32_bf16(af[1], wf[0], acc[1][0], 0, 0, 0);
        acc[0][1] = __builtin_amdgcn_mfma_f32_16x16x32_bf16(af[0], wf[1], acc[0][1], 0, 0, 0);
        acc[1][1] = __builtin_amdgcn_mfma_f32_16x16x32_bf16(af[1], wf[1], acc[1][1], 0, 0, 0);
    }

    // ---- merge K-halves + cell
    // C/D layout: col(r) = lane&15, row(m) = quad*4 + t.
#pragma unroll
    for (int mf = 0; mf < 2; ++mf)
#pragma unroll
        for (int rf = 0; rf < 2; ++rf)
#pragma unroll
            for (int t = 0; t < 4; ++t) {
                const int m = mf * 16 + quad * 4 + t;
                const int r = rf * 16 + ln;
                sPre[group][(gate * 32 + m) * 32 + r] = acc[mf][rf][t];
            }
    __syncthreads();

#pragma unroll
    for (int i = 0; i < 2; ++i) {
        const int ci = tid + i * 512;      // 0..1023 over 32m x 32r
        const int m = ci >> 5;
        const int r = ci & 31;
        const int gm = m_base + m;
        const int gr = rb + r;
        const float pI = sPre[0][(0 * 32 + m) * 32 + r] + sPre[1][(0 * 32 + m) * 32 + r]
                       + bi[0 * R_N + gr] + bh[0 * R_N + gr];
        const float pF = sPre[0][(1 * 32 + m) * 32 + r] + sPre[1][(1 * 32 + m) * 32 + r]
                       + bi[1 * R_N + gr] + bh[1 * R_N + gr];
        const float pO = sPre[0][(2 * 32 + m) * 32 + r] + sPre[1][(2 * 32 + m) * 32 + r]
                       + bi[2 * R_N + gr] + bh[2 * R_N + gr];
        const float pG = sPre[0][(3 * 32 + m) * 32 + r] + sPre[1][(3 * 32 + m) * 32 + r]
                       + bi[3 * R_N + gr] + bh[3 * R_N + gr];
        const size_t cidx = (size_t)gm * R_N + gr;
        const float cv = sigmoid_f(pF) * c_state[cidx] + sigmoid_f(pI) * tanh_f(pG);
        c_state[cidx] = cv;
        h_out[(size_t)gm * ldh + gr] = sigmoid_f(pO) * tanh_f(cv);
    }
}

// Unpack init_states_input (B, 4, R) -> h0 ws, c0 ws, out slot 0 (h1), c1 ws.
__global__ __launch_bounds__(256) void init_states(
    const float* __restrict__ st, float* __restrict__ h0,
    float* __restrict__ c0, float* __restrict__ c1, float* __restrict__ out)
{
    const int idx = blockIdx.x * 256 + threadIdx.x;  // 0 .. 256*1024-1
    const int b = idx >> 10;
    const int r = idx & 1023;
    const float* s = st + (size_t)b * 4096;
    h0[idx] = s[r];
    c0[idx] = s[1024 + r];
    out[(size_t)b * (U_N * R_N) + r] = s[2048 + r];
    c1[idx] = s[3072 + r];
}

extern "C" void kernel_launch(void* const* d_in, const int* in_sizes, int n_in,
                              void* d_out, int out_size, void* d_ws, size_t ws_size,
                              hipStream_t stream)
{
    const float* x   = (const float*)d_in[0];
    const float* st  = (const float*)d_in[1];
    const float* Wi0 = (const float*)d_in[2];
    const float* bi0 = (const float*)d_in[3];
    const float* Wh0 = (const float*)d_in[4];
    const float* bh0 = (const float*)d_in[5];
    const float* Wi1 = (const float*)d_in[6];
    const float* bi1 = (const float*)d_in[7];
    const float* Wh1 = (const float*)d_in[8];
    const float* bh1 = (const float*)d_in[9];
    float* out = (float*)d_out;

    float* h0a = (float*)d_ws;
    float* h0b = h0a + B_N * R_N;
    float* c0  = h0b + B_N * R_N;
    float* c1  = c0 + B_N * R_N;

    init_states<<<dim3((B_N * R_N) / 256), 256, 0, stream>>>(st, h0a, c0, c1, out);

    const dim3 grid(R_N / 32, B_N / 32);  // (32, 8) = 256 blocks, 1 per CU
    for (int u = 0; u < 10; ++u) {
        const float* h0_in = (u & 1) ? h0b : h0a;
        float* h0_out      = (u & 1) ? h0a : h0b;
        // Layer 0: pre0 = x @ Wi0[u]^T + h0 @ Wh0[u]^T + biases
        lstm_layer<<<grid, 512, 0, stream>>>(
            x, 512, 512, Wi0 + (size_t)u * 4096 * 512,
            h0_in, R_N, R_N, Wh0 + (size_t)u * 4096 * 1024,
            bi0 + (size_t)u * 4096, bh0 + (size_t)u * 4096,
            c0, h0_out, R_N);
        // Layer 1: pre1 = h0n @ Wi1[u]^T + h1 @ Wh1[u]^T + biases
        //   h1 input = out slot u; h1 output = out slot u+1.
        lstm_layer<<<grid, 512, 0, stream>>>(
            h0_out, R_N, R_N, Wi1 + (size_t)u * 4096 * 1024,
            out + (size_t)u * R_N, U_N * R_N, R_N, Wh1 + (size_t)u * 4096 * 1024,
            bi1 + (size_t)u * 4096, bh1 + (size_t)u * 4096,
            c1, out + (size_t)(u + 1) * R_N, U_N * R_N);
    }
}